// Round 12
// baseline (1057.629 us; speedup 1.0000x reference)
//
#include <hip/hip_runtime.h>
#include <hip/hip_bf16.h>

// MultiScaleAttention on MI355X (gfx950).
// R12: R11 + proj GEMM moved to the R1-verified 128x128 tile kernel
//     (gemm_bt128, 4 waves, 32KiB LDS -> ~4 blocks/CU). proj is TAIL-bound:
//     294 blocks @ 1 block/CU = 1.15 rounds -> round 2 runs 38 blocks on 256
//     CUs (67us). 128^2 -> 1176 blocks @ ~4/CU = 1.15 dense rounds (~53us).
//     Everything else byte-identical to R11 (best verified 1057us).
// Budget (R11 counters): QKV 466 (3-variant schedule plateau; VGPR-capped
//     structure) + cvt ~90 (BW floor) + attn ~90 (BW floor) + proj 67 +
//     transposes ~5 + harness ws-poison fill ~340 (uncontrollable).
// GEMM core (256^2): 8 waves, BK=64, 8-phase counted-vmcnt schedule,
//     conflict-free XOR-swizzled LDS, bijective XCD swizzle, swapped-operand
//     packed epilogue; QKV epilogue writes [b][w][3][12][64][64] bf16 with
//     the window-major row permute fused into A source addressing.
// attn: window-contiguous slabs, 40KB XOR-swizzled LDS, 4 blocks/CU.

typedef __bf16 bf16x8 __attribute__((ext_vector_type(8)));
typedef float f32x4 __attribute__((ext_vector_type(4)));

#define GLOBAL_AS __attribute__((address_space(1)))
#define LDS_AS __attribute__((address_space(3)))

__device__ __forceinline__ unsigned short f2bf(float f) {
    unsigned u = __builtin_bit_cast(unsigned, f);
    u += 0x7FFFu + ((u >> 16) & 1u);           // round-to-nearest-even
    return (unsigned short)(u >> 16);
}
__device__ __forceinline__ float bf2f(unsigned short h) {
    return __builtin_bit_cast(float, (unsigned)h << 16);
}

__device__ __forceinline__ void load16_to_lds(const void* g, void* l) {
    __builtin_amdgcn_global_load_lds((const GLOBAL_AS unsigned int*)g,
                                     (LDS_AS unsigned int*)l, 16, 0, 0);
}

// ---------------- pure streaming fp32 -> bf16 (16B out / thread) ----------------
__global__ __launch_bounds__(256)
void cvt_f32_bf16(const float* __restrict__ in,
                  unsigned short* __restrict__ out, long n8) {
    const long i = (long)blockIdx.x * blockDim.x + threadIdx.x;  // 8-elem unit
    if (i >= n8) return;
    float4 f0 = ((const float4*)in)[i * 2];
    float4 f1 = ((const float4*)in)[i * 2 + 1];
    uint4 o;
    o.x = (unsigned)f2bf(f0.x) | ((unsigned)f2bf(f0.y) << 16);
    o.y = (unsigned)f2bf(f0.z) | ((unsigned)f2bf(f0.w) << 16);
    o.z = (unsigned)f2bf(f1.x) | ((unsigned)f2bf(f1.y) << 16);
    o.w = (unsigned)f2bf(f1.z) | ((unsigned)f2bf(f1.w) << 16);
    ((uint4*)out)[i] = o;
}

// ------------- fused W[K][N] fp32 -> Wt[N][K] bf16 (both weights) -------------
__global__ void transpose_cvt2(const float* __restrict__ W0,
                               unsigned short* __restrict__ T0,
                               const float* __restrict__ W1,
                               unsigned short* __restrict__ T1) {
    __shared__ float tile[32][33];
    int bxi = blockIdx.x;
    const float* W; unsigned short* Wt; int N;
    if (bxi < 72) { W = W0; Wt = T0; N = 2304; }
    else          { W = W1; Wt = T1; N = 768; bxi -= 72; }
    const int K = 768;
    int bx = bxi * 32;                         // N offset
    int by = blockIdx.y * 32;                  // K offset
    int tx = threadIdx.x & 31, ty = threadIdx.x >> 5;   // ty 0..7
    #pragma unroll
    for (int i = 0; i < 32; i += 8)
        tile[ty + i][tx] = W[(size_t)(by + ty + i) * N + bx + tx];
    __syncthreads();
    #pragma unroll
    for (int i = 0; i < 32; i += 8)
        Wt[(size_t)(bx + ty + i) * K + by + tx] = f2bf(tile[tx][ty + i]);
}

// ---------------- 256^2 bf16 GEMM (QKV path) ----------------
#define VM_WAIT3 asm volatile("s_waitcnt vmcnt(3)" ::: "memory")
#define VM_WAIT2 asm volatile("s_waitcnt vmcnt(2)" ::: "memory")
#define VM_WAIT0 asm volatile("s_waitcnt vmcnt(0)" ::: "memory")

#define GPHASE(BUF, CSW, IH, LOADBG, STG, WAITS) do {                        \
    if (LOADBG) {                                                            \
        const unsigned short* bb = &ls[(BUF) * 32768 + 16384 + (CSW)];       \
        bg[0] = *(const bf16x8*)&bb[(wn +  0 + lane15) * 64];                \
        bg[1] = *(const bf16x8*)&bb[(wn + 16 + lane15) * 64];                \
        bg[2] = *(const bf16x8*)&bb[(wn + 32 + lane15) * 64];                \
        bg[3] = *(const bf16x8*)&bb[(wn + 48 + lane15) * 64];                \
    }                                                                        \
    {                                                                        \
        const unsigned short* ab = &ls[(BUF) * 32768 + (CSW)];               \
        af[0] = *(const bf16x8*)&ab[(wm + (IH)*64 +  0 + lane15) * 64];      \
        af[1] = *(const bf16x8*)&ab[(wm + (IH)*64 + 16 + lane15) * 64];      \
        af[2] = *(const bf16x8*)&ab[(wm + (IH)*64 + 32 + lane15) * 64];      \
        af[3] = *(const bf16x8*)&ab[(wm + (IH)*64 + 48 + lane15) * 64];      \
    }                                                                        \
    STG;                                                                     \
    WAITS;                                                                   \
    __builtin_amdgcn_s_barrier();                                            \
    asm volatile("s_waitcnt lgkmcnt(0)" ::: "memory");                       \
    __builtin_amdgcn_sched_barrier(0);                                       \
    __builtin_amdgcn_s_setprio(1);                                           \
    _Pragma("unroll")                                                        \
    for (int ii = 0; ii < 4; ++ii)                                           \
        _Pragma("unroll")                                                    \
        for (int j = 0; j < 4; ++j)                                          \
            acc[(IH)*4 + ii][j] = __builtin_amdgcn_mfma_f32_16x16x32_bf16(   \
                bg[j], af[ii], acc[(IH)*4 + ii][j], 0, 0, 0);                \
    __builtin_amdgcn_s_setprio(0);                                           \
    __builtin_amdgcn_s_barrier();                                            \
} while (0)

__global__ __launch_bounds__(512, 2)
void gemm_qkv256(const unsigned short* __restrict__ A,
                 const unsigned short* __restrict__ Bt,
                 const float* __restrict__ bias,
                 unsigned short* __restrict__ qout, int N, int K) {
    __shared__ alignas(16) unsigned short ls[65536];       // 128 KiB

    const int tid  = threadIdx.x;
    const int lane = tid & 63;
    const int wave = tid >> 6;          // 0..7
    const int wm = (wave >> 2) * 128;   // 0 / 128
    const int wn = (wave & 3) * 64;     // 0 / 64 / 128 / 192
    const int lane15 = lane & 15;
    const int quad   = lane >> 4;
    const int csw0 = ((quad    ) ^ (lane & 7)) * 8;        // ks = 0
    const int csw1 = ((quad + 4) ^ (lane & 7)) * 8;        // ks = 32

    // bijective XCD swizzle (m204)
    const int nwg = (int)(gridDim.x * gridDim.y);
    const int hid = (int)(blockIdx.y * gridDim.x + blockIdx.x);
    const int q8  = nwg >> 3, r8 = nwg & 7;
    const int xcd = hid & 7;
    const int lid = (xcd < r8 ? xcd * (q8 + 1) : r8 * (q8 + 1) + (xcd - r8) * q8)
                    + (hid >> 3);
    const int tileX = lid % (int)gridDim.x;
    const int tileY = lid / (int)gridDim.x;
    const long bm = (long)tileY * 256;
    const long bn = (long)tileX * 256;

    // staging: thread covers row (tid>>3) within each 64-row quarter, physical
    // chunk tid&7 -> global (logical) chunk lc = (tid&7) ^ (row&7).
    const int r0 = tid >> 3;                               // 0..63
    const int lc = (tid & 7) ^ (r0 & 7);
    // QKV: output row m' = bm + q*64 + r0 is window-major; source row in the
    // UNPERMUTED xb is b*3136 + t*49 + w.
    const unsigned short* gAq[4];
    #pragma unroll
    for (int q = 0; q < 4; ++q) {
        const int mq = (int)bm + q * 64 + r0;
        const int b  = mq / 3136;
        const int r3 = mq - b * 3136;
        const long srow = (long)b * 3136 + (long)(r3 & 63) * 49 + (r3 >> 6);
        gAq[q] = A + srow * (long)K + lc * 8;
    }
    const unsigned short* gB = Bt + (bn + r0) * (long)K + lc * 8;
    const int ldsWaveBase = wave * 512;    // ushorts (8 rows per wave)

    auto STAGE_A = [&](int buf, int q, int kt) {
        load16_to_lds(gAq[q] + kt * 64,
                      &ls[buf * 32768 + q * 4096 + ldsWaveBase]);
    };
    auto STAGE_B = [&](int buf, int q, int kt) {
        load16_to_lds(gB + (long)q * 64 * K + kt * 64,
                      &ls[buf * 32768 + 16384 + q * 4096 + ldsWaveBase]);
    };

    f32x4 acc[8][4] = {};
    bf16x8 af[4], bg[4];

    const int NT = K >> 6;             // K-tiles (12); NI = NT/2 iterations
    const int NI = NT >> 1;

    // prologue: K-tile 0 (8 quarters) + K-tile 1 A-q0/q2 -> 10 loads
    STAGE_A(0, 0, 0); STAGE_A(0, 1, 0); STAGE_A(0, 2, 0); STAGE_A(0, 3, 0);
    STAGE_B(0, 0, 0); STAGE_B(0, 1, 0); STAGE_B(0, 2, 0); STAGE_B(0, 3, 0);
    STAGE_A(1, 0, 1); STAGE_A(1, 2, 1);
    VM_WAIT2;                           // K-tile 0 landed (A1q0,q2 in flight)
    __builtin_amdgcn_s_barrier();

    for (int i = 0; i < NI; ++i) {
        const int t2 = 2 * i;
        const bool last = (i == NI - 1);
        // Stage plan (every load >= 2 phases in flight before its drain):
        //   ph0: A1q1,A1q3,B1q0(t+1) | ph1: B1q1..q3 | ph2: -
        //   ph3: B0q0..q2(t+2) + vmcnt(3) | ph4: B0q3,A0q0,A0q2
        //   ph5: A0q1,A0q3 | ph6: - | ph7: A1q0,A1q2(t+3) + vmcnt(2)
        GPHASE(0, csw0, 0, 1,
               { STAGE_A(1, 1, t2 + 1); STAGE_A(1, 3, t2 + 1); STAGE_B(1, 0, t2 + 1); },
               { (void)0; });
        GPHASE(0, csw0, 1, 0,
               { STAGE_B(1, 1, t2 + 1); STAGE_B(1, 2, t2 + 1); STAGE_B(1, 3, t2 + 1); },
               { (void)0; });
        GPHASE(0, csw1, 0, 1, { (void)0; }, { (void)0; });
        GPHASE(0, csw1, 1, 0,
               { if (!last) { STAGE_B(0, 0, t2 + 2); STAGE_B(0, 1, t2 + 2);
                              STAGE_B(0, 2, t2 + 2); } },
               { if (last) { VM_WAIT0; } else { VM_WAIT3; } });
        GPHASE(1, csw0, 0, 1,
               { if (!last) { STAGE_B(0, 3, t2 + 2); STAGE_A(0, 0, t2 + 2);
                              STAGE_A(0, 2, t2 + 2); } },
               { (void)0; });
        GPHASE(1, csw0, 1, 0,
               { if (!last) { STAGE_A(0, 1, t2 + 2); STAGE_A(0, 3, t2 + 2); } },
               { (void)0; });
        GPHASE(1, csw1, 0, 1, { (void)0; }, { (void)0; });
        GPHASE(1, csw1, 1, 0,
               { if (!last) { STAGE_A(1, 0, t2 + 3); STAGE_A(1, 2, t2 + 3); VM_WAIT2; } },
               { (void)0; });
    }

    // Epilogue: [b][w][sec][h][t][d]; wave's 64-col slab = one (sec,h)
    const int rbase = (int)(bm) + wm + lane15;
    const int colBase = (int)bn + wn;              // multiple of 64
    const int sec = colBase / 768;
    const int hh  = (colBase - sec * 768) >> 6;
    const long shOff = (long)sec * 49152 + hh * 4096 + quad * 4;
    float4 bv[4];
    #pragma unroll
    for (int j = 0; j < 4; ++j)
        bv[j] = *(const float4*)&bias[colBase + quad * 4 + j * 16];
    #pragma unroll
    for (int i = 0; i < 8; ++i) {
        const int m  = rbase + i * 16;             // window-major token idx
        const int b  = m / 3136;
        const int r3 = m - b * 3136;               // = w*64 + t
        unsigned short* rp = qout + (long)(b * 49 + (r3 >> 6)) * 147456
                                  + shOff + (long)(r3 & 63) * 64;
        #pragma unroll
        for (int j = 0; j < 4; ++j) {
            ushort4 s;
            s.x = f2bf(acc[i][j][0] + bv[j].x);
            s.y = f2bf(acc[i][j][1] + bv[j].y);
            s.z = f2bf(acc[i][j][2] + bv[j].z);
            s.w = f2bf(acc[i][j][3] + bv[j].w);
            *(ushort4*)(rp + j * 16) = s;
        }
    }
}

// ---------------- 128^2 bf16 GEMM, fp32 out (proj path; R1-verified) ----------------
// 128x128 tile, BK=64, 256 threads = 4 waves (2x2 of 64x64), 32 KiB LDS ->
// ~4 blocks/CU. 2-barrier loop; XOR-swizzled LDS (0 conflicts measured R1);
// swapped-operand packed float4 epilogue. proj is tail-bound at 256^2
// (294 blocks = 1.15 rounds @ 1 block/CU); 1176 blocks @ ~4/CU fixes it.
__global__ __launch_bounds__(256)
void gemm_bt128(const unsigned short* __restrict__ A,
                const unsigned short* __restrict__ Bt,
                const float* __restrict__ bias,
                float* __restrict__ C, int M, int N, int K) {
    __shared__ alignas(16) unsigned short lsA[128 * 64];
    __shared__ alignas(16) unsigned short lsB[128 * 64];

    const int tid  = threadIdx.x;
    const int lane = tid & 63;
    const int wave = tid >> 6;
    const int wm = (wave >> 1) * 64;
    const int wn = (wave & 1) * 64;

    const int nwg = (int)(gridDim.x * gridDim.y);
    const int hid = (int)(blockIdx.y * gridDim.x + blockIdx.x);
    int lid = hid;
    if ((nwg & 7) == 0) {                       // 1176 % 8 == 0 -> active
        const int cpx = nwg >> 3;
        lid = (hid & 7) * cpx + (hid >> 3);
    }
    const int tileX = lid % (int)gridDim.x;
    const int tileY = lid / (int)gridDim.x;
    const long bm = (long)tileY * 128;
    const long bn = (long)tileX * 128;

    const int arow  = tid >> 3;                               // 0..31, +32/it
    const int acolb = (((tid & 7) ^ ((tid >> 3) & 7)) * 16);  // swizzled byte col
    const char* gA = (const char*)A + ((bm + arow) * (long)K) * 2 + acolb;
    const char* gB = (const char*)Bt + ((bn + arow) * (long)K) * 2 + acolb;
    const long rowStep = (long)K * 2 * 32;
    const int ldsWaveBase = wave * 512;        // ushort units

    f32x4 acc[4][4] = {};

    for (int kt = 0; kt < K; kt += 64) {
        #pragma unroll
        for (int it = 0; it < 4; ++it) {
            load16_to_lds(gA + it * rowStep, &lsA[it * 2048 + ldsWaveBase]);
            load16_to_lds(gB + it * rowStep, &lsB[it * 2048 + ldsWaveBase]);
        }
        gA += 128; gB += 128;                  // advance 64 bf16 in K
        __syncthreads();
        #pragma unroll
        for (int ks = 0; ks < 64; ks += 32) {
            bf16x8 af[4], bg[4];
            const int colSwz = (ks + ((lane >> 4) & 3) * 8) ^ ((lane & 7) * 8);
            #pragma unroll
            for (int i = 0; i < 4; ++i) {
                const int rowA = wm + i * 16 + (lane & 15);
                af[i] = *(const bf16x8*)&lsA[rowA * 64 + colSwz];
                const int rowB = wn + i * 16 + (lane & 15);
                bg[i] = *(const bf16x8*)&lsB[rowB * 64 + colSwz];
            }
            #pragma unroll
            for (int i = 0; i < 4; ++i)
                #pragma unroll
                for (int j = 0; j < 4; ++j)
                    acc[i][j] = __builtin_amdgcn_mfma_f32_16x16x32_bf16(
                        bg[j], af[i], acc[i][j], 0, 0, 0);
        }
        __syncthreads();
    }

    const int lane15 = lane & 15;
    const int quad   = lane >> 4;
    const long rbase = bm + wm + lane15;
    const int  cbase = (int)bn + wn + quad * 4;
    #pragma unroll
    for (int j = 0; j < 4; ++j) {
        const int col = cbase + j * 16;
        const float4 bv = *(const float4*)&bias[col];
        #pragma unroll
        for (int i = 0; i < 4; ++i) {
            const long row = rbase + i * 16;
            const size_t idx = (size_t)row * N + col;
            float4 s;
            s.x = acc[i][j][0] + bv.x;
            s.y = acc[i][j][1] + bv.y;
            s.z = acc[i][j][2] + bv.z;
            s.w = acc[i][j][3] + bv.w;
            *(float4*)(C + idx) = s;
        }
    }
}

// ---------------- MFMA windowed attention ----------------
// qkv layout: [b][w][sec][h][t][d] (t=64 tokens, d=64) -> contiguous slabs.
// One wave = one (b,w,head); 4 waves/block. LDS 40960B (vT/ps stride 64 with
// XOR chunk swizzle: phys_chunk = logical_chunk ^ (row&7)) -> 4 blocks/CU.
__global__ __launch_bounds__(256, 4)
void attn_win_mfma(const unsigned short* __restrict__ qkv,
                   unsigned short* __restrict__ o) {
    const int hg = blockIdx.x;       // 0..2
    const int w  = blockIdx.y;       // 0..48
    const int b  = blockIdx.z;       // batch within chunk
    const int wave = threadIdx.x >> 6;
    const int lane = threadIdx.x & 63;
    const int h = hg * 4 + wave;
    const int l = lane & 15;
    const int quad = lane >> 4;

    __shared__ alignas(16) unsigned short vT[4][64 * 64];  // [d][t], swizzled
    __shared__ alignas(16) unsigned short ps[4][16 * 64];  // P[q][key], swizzled

    const long slab = (long)(b * 49 + w) * 147456;
    const long hOff = (long)h * 4096;

    // ---- q load + max-pool + 0.125 scale (exact in bf16) -> A-frags ----
    bf16x8 af[2];
    {
        const unsigned short* qr = qkv + slab + hOff + (long)l * 64 + quad * 8;
        float m0[8], m1[8];
        #pragma unroll
        for (int sg = 0; sg < 4; ++sg) {
            uint4 u0 = *(const uint4*)(qr + sg * 1024);
            uint4 u1 = *(const uint4*)(qr + sg * 1024 + 32);
            const unsigned short* p0 = (const unsigned short*)&u0;
            const unsigned short* p1 = (const unsigned short*)&u1;
            #pragma unroll
            for (int e = 0; e < 8; ++e) {
                float f0 = bf2f(p0[e]), f1 = bf2f(p1[e]);
                if (sg == 0) { m0[e] = f0; m1[e] = f1; }
                else { m0[e] = fmaxf(m0[e], f0); m1[e] = fmaxf(m1[e], f1); }
            }
        }
        unsigned short a0[8], a1[8];
        #pragma unroll
        for (int e = 0; e < 8; ++e) {
            a0[e] = f2bf(m0[e] * 0.125f);
            a1[e] = f2bf(m1[e] * 0.125f);
        }
        af[0] = __builtin_bit_cast(bf16x8, *(uint4*)a0);
        af[1] = __builtin_bit_cast(bf16x8, *(uint4*)a1);
    }

    // ---- v: stage transposed into LDS (XOR-swizzled, stride 64) ----
    {
        const unsigned short* vr = qkv + slab + 98304 + hOff + (long)lane * 64;
        unsigned short* vw = &vT[wave][0];
        const int ch = lane >> 3, le = lane & 7;
        #pragma unroll
        for (int i = 0; i < 8; ++i) {
            uint4 u = *(const uint4*)(vr + i * 8);
            const unsigned short* pe = (const unsigned short*)&u;
            #pragma unroll
            for (int e = 0; e < 8; ++e) {
                const int d = i * 8 + e;
                vw[d * 64 + ((ch ^ (d & 7)) << 3) + le] = pe[e];
            }
        }
    }

    // ---- k B-frags from global; S = qp @ k^T ----
    f32x4 Sc[4] = {};
    {
        bf16x8 bk0, bk1;
        __builtin_amdgcn_s_setprio(1);
        #pragma unroll
        for (int tt = 0; tt < 4; ++tt) {
            const unsigned short* kr =
                qkv + slab + 49152 + hOff + (long)(tt * 16 + l) * 64 + quad * 8;
            bk0 = __builtin_bit_cast(bf16x8, *(const uint4*)kr);
            bk1 = __builtin_bit_cast(bf16x8, *(const uint4*)(kr + 32));
            Sc[tt] = __builtin_amdgcn_mfma_f32_16x16x32_bf16(af[0], bk0, Sc[tt], 0, 0, 0);
            Sc[tt] = __builtin_amdgcn_mfma_f32_16x16x32_bf16(af[1], bk1, Sc[tt], 0, 0, 0);
        }
        __builtin_amdgcn_s_setprio(0);
    }

    // ---- softmax: row q = quad*4+r, keys spread over 4 tt x 16 lanes ----
    float pr[4][4];
    {
        #pragma unroll
        for (int r = 0; r < 4; ++r) {
            float mx = fmaxf(fmaxf(Sc[0][r], Sc[1][r]), fmaxf(Sc[2][r], Sc[3][r]));
            #pragma unroll
            for (int off = 1; off < 16; off <<= 1)
                mx = fmaxf(mx, __shfl_xor(mx, off));
            float sum = 0.f;
            #pragma unroll
            for (int tt = 0; tt < 4; ++tt) {
                pr[tt][r] = __expf(Sc[tt][r] - mx);
                sum += pr[tt][r];
            }
            #pragma unroll
            for (int off = 1; off < 16; off <<= 1)
                sum += __shfl_xor(sum, off);
            const float inv = 1.0f / sum;
            #pragma unroll
            for (int tt = 0; tt < 4; ++tt) pr[tt][r] *= inv;
        }
    }

    // ---- P -> LDS (bf16, XOR-swizzled, stride 64) ----
    {
        unsigned short* pw = &ps[wave][0];
        #pragma unroll
        for (int r = 0; r < 4; ++r) {
            const int row = quad * 4 + r;
            #pragma unroll
            for (int tt = 0; tt < 4; ++tt) {
                const int c = (tt << 1) + (l >> 3);
                pw[row * 64 + ((c ^ (row & 7)) << 3) + (l & 7)] = f2bf(pr[tt][r]);
            }
        }
    }

    // ---- O = P @ v ----
    f32x4 Oc[4] = {};
    {
        __builtin_amdgcn_s_setprio(1);
        #pragma unroll
        for (int s = 0; s < 2; ++s) {
            const int csw = (((s << 2) + quad) ^ (l & 7)) << 3;
            bf16x8 ap = *(const bf16x8*)&ps[wave][l * 64 + csw];
            #pragma unroll
            for (int tt = 0; tt < 4; ++tt) {
                bf16x8 bv = *(const bf16x8*)&vT[wave][(tt * 16 + l) * 64 + csw];
                Oc[tt] = __builtin_amdgcn_mfma_f32_16x16x32_bf16(ap, bv, Oc[tt], 0, 0, 0);
            }
        }
        __builtin_amdgcn_s_setprio(0);
    }

    // ---- store: o row = b*784 + q*49 + w, col = h*64 + tt*16 + l ----
    {
        const long obase = ((long)b * 784 + (long)(quad * 4) * 49 + w) * 768 + h * 64 + l;
        #pragma unroll
        for (int tt = 0; tt < 4; ++tt)
            #pragma unroll
            for (int r = 0; r < 4; ++r)
                o[obase + (long)r * 49 * 768 + tt * 16] = f2bf(Oc[tt][r]);
    }
}

// ---------------- launcher ----------------
extern "C" void kernel_launch(void* const* d_in, const int* in_sizes, int n_in,
                              void* d_out, int out_size, void* d_ws, size_t ws_size,
                              hipStream_t stream) {
    const float* x     = (const float*)d_in[0];  // [32,3136,768]
    const float* Wqkv  = (const float*)d_in[1];  // [768,2304]
    const float* bqkv  = (const float*)d_in[2];  // [2304]
    const float* Wproj = (const float*)d_in[3];  // [768,768]
    const float* bproj = (const float*)d_in[4];  // [768]
    float* out = (float*)d_out;                  // [32,784,768] fp32

    const long needed1 = (32L * 3136 * 768 + 32L * 3136 * 2304 +
                          25088L * 768 + 2304L * 768 + 768L * 768) * 2;
    const int C  = (ws_size >= (size_t)needed1) ? 1 : 4;   // unchunked if ws allows
    const int CB = 32 / C;
    const long XC = (long)CB * 3136 * 768;
    const long QC = (long)CB * 3136 * 2304;

    char* p = (char*)d_ws;
    unsigned short* xb    = (unsigned short*)p; p += XC * 2;
    unsigned short* qkvb  = (unsigned short*)p; p += QC * 2;
    unsigned short* ob    = (unsigned short*)p; p += 25088L * 768 * 2;
    unsigned short* WqkvT = (unsigned short*)p; p += 2304L * 768 * 2;
    unsigned short* WprojT= (unsigned short*)p; p += 768L * 768 * 2;

    transpose_cvt2<<<dim3(96, 24), 256, 0, stream>>>(Wqkv, WqkvT, Wproj, WprojT);

    const int M = CB * 3136;
    for (int c = 0; c < C; ++c) {
        cvt_f32_bf16<<<(int)((M * 96L + 255) / 256), 256, 0, stream>>>(
            x + (size_t)c * XC, xb, M * 96L);
        gemm_qkv256<<<dim3(9, M / 256), 512, 0, stream>>>(
            xb, WqkvT, bqkv, qkvb, 2304, 768);
        attn_win_mfma<<<dim3(3, 49, CB), 256, 0, stream>>>(
            qkvb, ob + (size_t)c * CB * 784 * 768);
    }
    gemm_bt128<<<dim3(6, 196), 256, 0, stream>>>(
        ob, WprojT, bproj, out, 25088, 768, 768);
}